// Round 4
// baseline (165.574 us; speedup 1.0000x reference)
//
#include <hip/hip_runtime.h>

typedef __attribute__((ext_vector_type(8))) short bf16x8;
typedef __attribute__((ext_vector_type(4))) float f32x4;

#define AS3 __attribute__((address_space(3)))
#define AS1 __attribute__((address_space(1)))

__device__ __forceinline__ unsigned short f2bf(float f) {
  unsigned u = __float_as_uint(f);
  u += 0x7fffu + ((u >> 16) & 1u);
  return (unsigned short)(u >> 16);
}
__device__ __forceinline__ float bf2f(unsigned short v) {
  return __uint_as_float((unsigned)v << 16);
}

// ---------------- kernel 1: transpose + pad + bf16 convert + pooled partial sums
// x[b][c][y][x] -> xTp[b][(y+1)*66+(x+1)][c] bf16; atomicAdd channel sums into pooled
__global__ void transpose_kernel(const float* __restrict__ x,
                                 unsigned short* __restrict__ xTp,
                                 float* __restrict__ pooled) {
  __shared__ unsigned short tb[64][258];
  const int blk = blockIdx.x;
  const int b = blk >> 6, y = blk & 63;
  const int t = threadIdx.x;
  const int xcol = t & 63;
  const int cbase = t >> 6;
  const float* src = x + (size_t)b * 256 * 4096 + (size_t)y * 64;
  for (int it = 0; it < 64; ++it) {
    const int c = it * 4 + cbase;
    tb[xcol][c] = f2bf(src[(size_t)c * 4096 + xcol]);
  }
  __syncthreads();
  unsigned short* dst = xTp + (size_t)b * (4356 * 256) + ((size_t)(y + 1) * 66 + 1) * 256;
  const int wv = t >> 6, ln = t & 63;
  float p0 = 0.f, p1 = 0.f, p2 = 0.f, p3 = 0.f;
  for (int i = 0; i < 16; ++i) {
    const int xx = wv * 16 + i;
    ushort2 v0 = *(const ushort2*)&tb[xx][ln * 4];
    ushort2 v1 = *(const ushort2*)&tb[xx][ln * 4 + 2];
    p0 += bf2f(v0.x); p1 += bf2f(v0.y); p2 += bf2f(v1.x); p3 += bf2f(v1.y);
    ushort4 v = {v0.x, v0.y, v1.x, v1.y};
    *(ushort4*)&dst[(size_t)xx * 256 + ln * 4] = v;
  }
  atomicAdd(&pooled[b * 256 + ln * 4 + 0], p0 * (1.0f / 4096.0f));
  atomicAdd(&pooled[b * 256 + ln * 4 + 1], p1 * (1.0f / 4096.0f));
  atomicAdd(&pooled[b * 256 + ln * 4 + 2], p2 * (1.0f / 4096.0f));
  atomicAdd(&pooled[b * 256 + ln * 4 + 3], p3 * (1.0f / 4096.0f));
}

// ---------------- kernel 1b: zero the pad borders of xTp ----------------
__global__ void border_kernel(unsigned short* __restrict__ xTp) {
  const int br = blockIdx.x;  // 0..259
  const int b = blockIdx.y;
  int y, xx;
  if (br < 66) { y = 0; xx = br; }
  else if (br < 132) { y = 65; xx = br - 66; }
  else { const int k = br - 132; y = 1 + (k >> 1); xx = (k & 1) * 65; }
  xTp[((size_t)b * 4356 + y * 66 + xx) * 256 + threadIdx.x] = 0;
}

// ---------------- kernel 2: attention MLP + softmax ----------------
__global__ void attn_kernel(const float* __restrict__ pooled,
                            const float* __restrict__ w1,
                            const float* __restrict__ bng,
                            const float* __restrict__ bnb,
                            const float* __restrict__ bnm,
                            const float* __restrict__ bnv,
                            const float* __restrict__ w2,
                            float* __restrict__ att) {
  __shared__ float hbuf[256];
  const int t = threadIdx.x;
  const int b = t >> 4, i = t & 15;
  float s = 0.f;
  for (int c = 0; c < 256; ++c) s += pooled[b * 256 + c] * w1[i * 256 + c];
  float h = (s - bnm[i]) * rsqrtf(bnv[i] + 1e-5f) * bng[i] + bnb[i];
  hbuf[t] = fmaxf(h, 0.f);
  __syncthreads();
  if (t < 64) {
    const int bb = t >> 2, k = t & 3;
    float l = 0.f;
    for (int j = 0; j < 16; ++j) l += hbuf[bb * 16 + j] * w2[k * 16 + j];
    float m = l;
    m = fmaxf(m, __shfl_xor(m, 1, 64));
    m = fmaxf(m, __shfl_xor(m, 2, 64));
    float e = expf(l - m);
    float sum = e;
    sum += __shfl_xor(sum, 1, 64);
    sum += __shfl_xor(sum, 2, 64);
    att[bb * 4 + k] = e / sum;
  }
}

// ---------------- kernel 3: aggregate per-sample kernels ----------------
// block per cout o; weights loaded once, reused across 16 samples
__global__ void agg_kernel(const float* __restrict__ att,
                           const float* __restrict__ wgt,
                           unsigned short* __restrict__ agg) {
  const int o = blockIdx.x;   // 256
  const int c = threadIdx.x;  // 256
  float w[4][9];
#pragma unroll
  for (int k = 0; k < 4; ++k) {
    const float* wp = wgt + ((size_t)((k << 8) + o) * 256 + c) * 9;
#pragma unroll
    for (int t = 0; t < 9; ++t) w[k][t] = wp[t];
  }
  __shared__ float attS[64];
  if (c < 64) attS[c] = att[c];
  __syncthreads();
#pragma unroll 1
  for (int b = 0; b < 16; ++b) {
    const float a0 = attS[b * 4 + 0], a1 = attS[b * 4 + 1];
    const float a2 = attS[b * 4 + 2], a3 = attS[b * 4 + 3];
#pragma unroll
    for (int t = 0; t < 9; ++t) {
      const float v = a0 * w[0][t] + a1 * w[1][t] + a2 * w[2][t] + a3 * w[3][t];
      agg[(((size_t)(b * 9 + t) * 256) + o) * 256 + c] = f2bf(v);
    }
  }
}

// ---------------- kernel 4: per-sample implicit-GEMM conv (bf16 MFMA) ----
// tile 256(p) x 128(cout), A-halo (396 contiguous xTp rows) staged once per
// c0-slice and reused across 9 taps; B ring-4 depth-2 counted vmcnt.
// 2 blocks/CU (64 KiB LDS). 8 waves = 4M x 2N, per-wave 64x64 (4x4 frags).
__global__ __launch_bounds__(512, 4) void conv_kernel(
    const unsigned short* __restrict__ xTp,
    const unsigned short* __restrict__ agg,
    float* __restrict__ out) {
  __shared__ unsigned short lds[512 * 32 + 4 * 128 * 32];  // 64 KiB
  AS3 char* ldsA3 = (AS3 char*)lds;               // A: 512 rows x 64 B
  AS3 char* ldsB3 = (AS3 char*)(lds + 512 * 32);  // B: 4 slots x 8 KiB

  const int bid = blockIdx.x;
  const int b = bid & 15;   // XCD = b%8: all 32 blocks of a sample co-XCD
  const int rest = bid >> 4;
  const int mt = rest >> 1;  // 0..15  p-tile
  const int nh = rest & 1;   // 0..1   cout half
  const int p0 = mt << 8;
  const int rowA0 = mt * 264;  // halo base row = mt*4*66 (396 contiguous rows)

  const int tid = threadIdx.x;
  const int lane = tid & 63;
  const int wave = tid >> 6;
  const int wm = wave >> 1;  // 0..3
  const int wn = wave & 1;   // 0..1

  // staging: thread t -> LDS row srow(+128*i), linear slot t&3;
  // source col pre-swizzled by swz(row) = (row>>1)&3 = (t>>3)&3
  const int srow = tid >> 2;
  const int scol = ((tid & 3) ^ ((tid >> 3) & 3)) << 3;
  const int sdst = srow * 64 + (tid & 3) * 16;

  const unsigned short* xbs =
      xTp + (size_t)b * (4356 * 256) + (size_t)rowA0 * 256 + scol;
  const unsigned short* aggs =
      agg + ((size_t)(b * 9) * 256 + nh * 128 + srow) * 256 + scol;

  auto stageA = [&](int c0) {
#pragma unroll
    for (int i = 0; i < 4; ++i) {
      const int h = srow + (i << 7);
      const int hs = h > 395 ? 395 : h;  // clamp source; dest rows 396..511 unused
      __builtin_amdgcn_global_load_lds(
          (const AS1 void*)(xbs + (size_t)hs * 256 + c0 * 32),
          (AS3 void*)(ldsA3 + sdst + (i << 13)), 16, 0, 0);
    }
  };
  auto stageB = [&](int c02, int tap2, int slot) {
    __builtin_amdgcn_global_load_lds(
        (const AS1 void*)(aggs + tap2 * 65536 + c02 * 32),
        (AS3 void*)(ldsB3 + slot * 8192 + sdst), 16, 0, 0);
  };

  // fragment read offsets
  const int l15 = lane & 15;
  const int lhi = lane >> 4;
  const int hb = wm * 66 + l15;  // per-lane A halo row base (tap 0,0 / m=0)
  const int rslotB = (lhi ^ ((l15 >> 1) & 3)) << 4;
  int boffs[4];
#pragma unroll
  for (int n = 0; n < 4; ++n)
    boffs[n] = 32768 * 2 /*bytes: 512*32*2*/ + (wn * 64 + n * 16 + l15) * 64 + rslotB;
  // note: ldsB3 byte base = 512*32*2 = 32768 bytes; boffs is absolute byte off
  // (32768*2 above is wrong if lds element size misread — compute explicitly)
  // lds is unsigned short: byte offset of B region = 512*32*2 = 32768.
#pragma unroll
  for (int n = 0; n < 4; ++n)
    boffs[n] = 32768 + (wn * 64 + n * 16 + l15) * 64 + rslotB;

  f32x4 acc[4][4];
#pragma unroll
  for (int m = 0; m < 4; ++m)
#pragma unroll
    for (int n = 0; n < 4; ++n) acc[m][n] = (f32x4){0.f, 0.f, 0.f, 0.f};

  // prologue: B[0], B[1]
  stageB(0, 0, 0);
  stageB(0, 1, 1);

#pragma unroll 1
  for (int c0 = 0; c0 < 8; ++c0) {
    __builtin_amdgcn_s_barrier();  // all waves done reading A[c0-1]
    stageA(c0);
    asm volatile("s_waitcnt vmcnt(0)" ::: "memory");  // A + pending B landed
    __builtin_amdgcn_s_barrier();
#pragma unroll
    for (int tap = 0; tap < 9; ++tap) {
      if (tap != 0) {
        asm volatile("s_waitcnt vmcnt(1)" ::: "memory");  // B[ks] landed
        __builtin_amdgcn_s_barrier();
      }
      __builtin_amdgcn_sched_barrier(0);
      const int dy = tap / 3, dx = tap % 3;
      const int slotR = (c0 + tap) & 3;  // (9c0+tap)&3
      bf16x8 af[4], bfr[4];
#pragma unroll
      for (int m = 0; m < 4; ++m) {
        const int h = hb + dy * 66 + dx + m * 16;
        const int ab = h * 64 + ((lhi ^ ((h >> 1) & 3)) << 4);
        af[m] = *(const bf16x8*)((const char*)lds + ab);
      }
#pragma unroll
      for (int n = 0; n < 4; ++n)
        bfr[n] = *(const bf16x8*)((const char*)lds + slotR * 8192 + boffs[n]);
      // stage B[ks+2] (depth-2)
      int c02, tap2;
      if (tap <= 6) { c02 = c0; tap2 = tap + 2; }
      else { c02 = c0 + 1; tap2 = tap - 7; }
      if (c02 > 7) { c02 = 7; tap2 = 8; }  // tail dup, keeps vmcnt uniform
      stageB(c02, tap2, (c0 + tap + 2) & 3);
      __builtin_amdgcn_s_setprio(1);
#pragma unroll
      for (int m = 0; m < 4; ++m)
#pragma unroll
        for (int n = 0; n < 4; ++n)
          acc[m][n] = __builtin_amdgcn_mfma_f32_16x16x32_bf16(af[m], bfr[n],
                                                              acc[m][n], 0, 0, 0);
      __builtin_amdgcn_s_setprio(0);
    }
  }

  // epilogue: D row=(lane>>4)*4+reg is p, col=lane&15 is cout
#pragma unroll
  for (int m = 0; m < 4; ++m) {
    const int p = p0 + wm * 64 + m * 16 + (lhi << 2);
#pragma unroll
    for (int n = 0; n < 4; ++n) {
      const int co = nh * 128 + wn * 64 + n * 16 + l15;
      float* dst = out + ((size_t)(b * 256 + co) << 12) + p;
      *reinterpret_cast<f32x4*>(dst) = acc[m][n];
    }
  }
}

extern "C" void kernel_launch(void* const* d_in, const int* in_sizes, int n_in,
                              void* d_out, int out_size, void* d_ws, size_t ws_size,
                              hipStream_t stream) {
  const float* x = (const float*)d_in[0];
  const float* w1 = (const float*)d_in[1];
  const float* bng = (const float*)d_in[2];
  const float* bnb = (const float*)d_in[3];
  const float* bnm = (const float*)d_in[4];
  const float* bnv = (const float*)d_in[5];
  const float* w2 = (const float*)d_in[6];
  const float* wgt = (const float*)d_in[7];
  float* out = (float*)d_out;

  char* ws = (char*)d_ws;
  const size_t xtp_bytes = (size_t)16 * 4356 * 256 * 2;    // 35,684,352
  const size_t agg_bytes = (size_t)16 * 9 * 256 * 256 * 2; // 18,874,368
  unsigned short* xTp = (unsigned short*)ws;
  unsigned short* agg = (unsigned short*)(ws + xtp_bytes);
  float* pooled = (float*)(ws + xtp_bytes + agg_bytes);
  float* att = (float*)(ws + xtp_bytes + agg_bytes + 16384);

  hipMemsetAsync(pooled, 0, 16 * 256 * sizeof(float), stream);
  border_kernel<<<dim3(260, 16), 256, 0, stream>>>(xTp);
  transpose_kernel<<<1024, 256, 0, stream>>>(x, xTp, pooled);
  attn_kernel<<<1, 256, 0, stream>>>(pooled, w1, bng, bnb, bnm, bnv, w2, att);
  agg_kernel<<<256, 256, 0, stream>>>(att, wgt, agg);
  conv_kernel<<<512, 512, 0, stream>>>(xTp, agg, out);
}

// Round 5
// 122.018 us; speedup vs baseline: 1.3570x; 1.3570x over previous
//
#include <hip/hip_runtime.h>

typedef __attribute__((ext_vector_type(8))) short bf16x8;
typedef __attribute__((ext_vector_type(4))) float f32x4;

#define AS3 __attribute__((address_space(3)))
#define AS1 __attribute__((address_space(1)))

__device__ __forceinline__ unsigned short f2bf(float f) {
  unsigned u = __float_as_uint(f);
  u += 0x7fffu + ((u >> 16) & 1u);
  return (unsigned short)(u >> 16);
}

// ---------------- kernel 0: global average pool (atomic-free, R1 design) ----
// x viewed as [B*CIN][4096] -> pooled[B*CIN]
__global__ void pool_kernel(const float* __restrict__ x, float* __restrict__ pooled) {
  const int bc = blockIdx.x;
  const float4* p = reinterpret_cast<const float4*>(x) + (size_t)bc * 1024;
  float s = 0.f;
  for (int i = threadIdx.x; i < 1024; i += 256) {
    float4 v = p[i];
    s += v.x + v.y + v.z + v.w;
  }
#pragma unroll
  for (int off = 32; off > 0; off >>= 1) s += __shfl_xor(s, off, 64);
  __shared__ float wsum[4];
  if ((threadIdx.x & 63) == 0) wsum[threadIdx.x >> 6] = s;
  __syncthreads();
  if (threadIdx.x == 0)
    pooled[bc] = (wsum[0] + wsum[1] + wsum[2] + wsum[3]) * (1.0f / 4096.0f);
}

// ---------------- kernel 1: transpose + pad + bf16 convert (pure) ----------
// x[b][c][y][x] -> xTp[b][(y+1)*66+(x+1)][c] bf16 (borders zeroed separately)
// Read: wave instruction covers 4 full channel-rows (1KB contiguous).
__global__ void transpose_kernel(const float* __restrict__ x,
                                 unsigned short* __restrict__ xTp) {
  __shared__ unsigned short tb[64][258];
  const int blk = blockIdx.x;
  const int b = blk >> 6, y = blk & 63;
  const int t = threadIdx.x;
  const int l = t & 63, w = t >> 6;
  const int coff = l >> 4;          // 0..3 channel sub-offset
  const int x4 = (l & 15) << 2;     // 0..60 x base
  const float* src = x + (size_t)b * 256 * 4096 + (size_t)y * 64;
#pragma unroll 4
  for (int i = 0; i < 16; ++i) {
    const int c = w * 64 + i * 4 + coff;
    const float4 v = *reinterpret_cast<const float4*>(&src[(size_t)c * 4096 + x4]);
    tb[x4 + 0][c] = f2bf(v.x);
    tb[x4 + 1][c] = f2bf(v.y);
    tb[x4 + 2][c] = f2bf(v.z);
    tb[x4 + 3][c] = f2bf(v.w);
  }
  __syncthreads();
  unsigned short* dst = xTp + (size_t)b * (4356 * 256) + ((size_t)(y + 1) * 66 + 1) * 256;
#pragma unroll 4
  for (int i = 0; i < 16; ++i) {
    const int xx = w * 16 + i;
    ushort2 v0 = *(const ushort2*)&tb[xx][l * 4];
    ushort2 v1 = *(const ushort2*)&tb[xx][l * 4 + 2];
    ushort4 v = {v0.x, v0.y, v1.x, v1.y};
    *(ushort4*)&dst[(size_t)xx * 256 + l * 4] = v;
  }
}

// ---------------- kernel 1b: zero the pad borders of xTp ----------------
__global__ void border_kernel(unsigned short* __restrict__ xTp) {
  const int br = blockIdx.x;  // 0..259
  const int b = blockIdx.y;
  int y, xx;
  if (br < 66) { y = 0; xx = br; }
  else if (br < 132) { y = 65; xx = br - 66; }
  else { const int k = br - 132; y = 1 + (k >> 1); xx = (k & 1) * 65; }
  xTp[((size_t)b * 4356 + y * 66 + xx) * 256 + threadIdx.x] = 0;
}

// ---------------- kernel 2: attention MLP + softmax ----------------
__global__ void attn_kernel(const float* __restrict__ pooled,
                            const float* __restrict__ w1,
                            const float* __restrict__ bng,
                            const float* __restrict__ bnb,
                            const float* __restrict__ bnm,
                            const float* __restrict__ bnv,
                            const float* __restrict__ w2,
                            float* __restrict__ att) {
  __shared__ float hbuf[256];
  const int t = threadIdx.x;
  const int b = t >> 4, i = t & 15;
  float s = 0.f;
  for (int c = 0; c < 256; ++c) s += pooled[b * 256 + c] * w1[i * 256 + c];
  float h = (s - bnm[i]) * rsqrtf(bnv[i] + 1e-5f) * bng[i] + bnb[i];
  hbuf[t] = fmaxf(h, 0.f);
  __syncthreads();
  if (t < 64) {
    const int bb = t >> 2, k = t & 3;
    float l = 0.f;
    for (int j = 0; j < 16; ++j) l += hbuf[bb * 16 + j] * w2[k * 16 + j];
    float m = l;
    m = fmaxf(m, __shfl_xor(m, 1, 64));
    m = fmaxf(m, __shfl_xor(m, 2, 64));
    float e = expf(l - m);
    float sum = e;
    sum += __shfl_xor(sum, 1, 64);
    sum += __shfl_xor(sum, 2, 64);
    att[bb * 4 + k] = e / sum;
  }
}

// ---------------- kernel 3: aggregate per-sample kernels ----------------
// block (o, b-half); weights loaded once per block, reused across 8 samples
__global__ void agg_kernel(const float* __restrict__ att,
                           const float* __restrict__ wgt,
                           unsigned short* __restrict__ agg) {
  const int o = blockIdx.x;    // 256
  const int bh = blockIdx.y;   // 0..1
  const int c = threadIdx.x;   // 256
  float w[4][9];
#pragma unroll
  for (int k = 0; k < 4; ++k) {
    const float* wp = wgt + ((size_t)((k << 8) + o) * 256 + c) * 9;
#pragma unroll
    for (int t = 0; t < 9; ++t) w[k][t] = wp[t];
  }
  __shared__ float attS[64];
  if (c < 64) attS[c] = att[c];
  __syncthreads();
#pragma unroll 1
  for (int b = bh * 8; b < bh * 8 + 8; ++b) {
    const float a0 = attS[b * 4 + 0], a1 = attS[b * 4 + 1];
    const float a2 = attS[b * 4 + 2], a3 = attS[b * 4 + 3];
#pragma unroll
    for (int t = 0; t < 9; ++t) {
      const float v = a0 * w[0][t] + a1 * w[1][t] + a2 * w[2][t] + a3 * w[3][t];
      agg[(((size_t)(b * 9 + t) * 256) + o) * 256 + c] = f2bf(v);
    }
  }
}

// ---------------- kernel 4: per-sample implicit-GEMM conv (bf16 MFMA) ----
// UNCHANGED from R4 (need its counters this round).
// tile 256(p) x 128(cout), A-halo (396 contiguous xTp rows) staged once per
// c0-slice and reused across 9 taps; B ring-4 depth-2 counted vmcnt.
__global__ __launch_bounds__(512, 4) void conv_kernel(
    const unsigned short* __restrict__ xTp,
    const unsigned short* __restrict__ agg,
    float* __restrict__ out) {
  __shared__ unsigned short lds[512 * 32 + 4 * 128 * 32];  // 64 KiB
  AS3 char* ldsA3 = (AS3 char*)lds;               // A: 512 rows x 64 B
  AS3 char* ldsB3 = (AS3 char*)(lds + 512 * 32);  // B: 4 slots x 8 KiB

  const int bid = blockIdx.x;
  const int b = bid & 15;
  const int rest = bid >> 4;
  const int mt = rest >> 1;
  const int nh = rest & 1;
  const int p0 = mt << 8;
  const int rowA0 = mt * 264;

  const int tid = threadIdx.x;
  const int lane = tid & 63;
  const int wave = tid >> 6;
  const int wm = wave >> 1;
  const int wn = wave & 1;

  const int srow = tid >> 2;
  const int scol = ((tid & 3) ^ ((tid >> 3) & 3)) << 3;
  const int sdst = srow * 64 + (tid & 3) * 16;

  const unsigned short* xbs =
      xTp + (size_t)b * (4356 * 256) + (size_t)rowA0 * 256 + scol;
  const unsigned short* aggs =
      agg + ((size_t)(b * 9) * 256 + nh * 128 + srow) * 256 + scol;

  auto stageA = [&](int c0) {
#pragma unroll
    for (int i = 0; i < 4; ++i) {
      const int h = srow + (i << 7);
      const int hs = h > 395 ? 395 : h;
      __builtin_amdgcn_global_load_lds(
          (const AS1 void*)(xbs + (size_t)hs * 256 + c0 * 32),
          (AS3 void*)(ldsA3 + sdst + (i << 13)), 16, 0, 0);
    }
  };
  auto stageB = [&](int c02, int tap2, int slot) {
    __builtin_amdgcn_global_load_lds(
        (const AS1 void*)(aggs + tap2 * 65536 + c02 * 32),
        (AS3 void*)(ldsB3 + slot * 8192 + sdst), 16, 0, 0);
  };

  const int l15 = lane & 15;
  const int lhi = lane >> 4;
  const int hb = wm * 66 + l15;
  const int rslotB = (lhi ^ ((l15 >> 1) & 3)) << 4;
  int boffs[4];
#pragma unroll
  for (int n = 0; n < 4; ++n)
    boffs[n] = 32768 + (wn * 64 + n * 16 + l15) * 64 + rslotB;

  f32x4 acc[4][4];
#pragma unroll
  for (int m = 0; m < 4; ++m)
#pragma unroll
    for (int n = 0; n < 4; ++n) acc[m][n] = (f32x4){0.f, 0.f, 0.f, 0.f};

  stageB(0, 0, 0);
  stageB(0, 1, 1);

#pragma unroll 1
  for (int c0 = 0; c0 < 8; ++c0) {
    __builtin_amdgcn_s_barrier();
    stageA(c0);
    asm volatile("s_waitcnt vmcnt(0)" ::: "memory");
    __builtin_amdgcn_s_barrier();
#pragma unroll
    for (int tap = 0; tap < 9; ++tap) {
      if (tap != 0) {
        asm volatile("s_waitcnt vmcnt(1)" ::: "memory");
        __builtin_amdgcn_s_barrier();
      }
      __builtin_amdgcn_sched_barrier(0);
      const int dy = tap / 3, dx = tap % 3;
      const int slotR = (c0 + tap) & 3;
      bf16x8 af[4], bfr[4];
#pragma unroll
      for (int m = 0; m < 4; ++m) {
        const int h = hb + dy * 66 + dx + m * 16;
        const int ab = h * 64 + ((lhi ^ ((h >> 1) & 3)) << 4);
        af[m] = *(const bf16x8*)((const char*)lds + ab);
      }
#pragma unroll
      for (int n = 0; n < 4; ++n)
        bfr[n] = *(const bf16x8*)((const char*)lds + slotR * 8192 + boffs[n]);
      int c02, tap2;
      if (tap <= 6) { c02 = c0; tap2 = tap + 2; }
      else { c02 = c0 + 1; tap2 = tap - 7; }
      if (c02 > 7) { c02 = 7; tap2 = 8; }
      stageB(c02, tap2, (c0 + tap + 2) & 3);
      __builtin_amdgcn_s_setprio(1);
#pragma unroll
      for (int m = 0; m < 4; ++m)
#pragma unroll
        for (int n = 0; n < 4; ++n)
          acc[m][n] = __builtin_amdgcn_mfma_f32_16x16x32_bf16(af[m], bfr[n],
                                                              acc[m][n], 0, 0, 0);
      __builtin_amdgcn_s_setprio(0);
    }
  }

#pragma unroll
  for (int m = 0; m < 4; ++m) {
    const int p = p0 + wm * 64 + m * 16 + (lhi << 2);
#pragma unroll
    for (int n = 0; n < 4; ++n) {
      const int co = nh * 128 + wn * 64 + n * 16 + l15;
      float* dst = out + ((size_t)(b * 256 + co) << 12) + p;
      *reinterpret_cast<f32x4*>(dst) = acc[m][n];
    }
  }
}

extern "C" void kernel_launch(void* const* d_in, const int* in_sizes, int n_in,
                              void* d_out, int out_size, void* d_ws, size_t ws_size,
                              hipStream_t stream) {
  const float* x = (const float*)d_in[0];
  const float* w1 = (const float*)d_in[1];
  const float* bng = (const float*)d_in[2];
  const float* bnb = (const float*)d_in[3];
  const float* bnm = (const float*)d_in[4];
  const float* bnv = (const float*)d_in[5];
  const float* w2 = (const float*)d_in[6];
  const float* wgt = (const float*)d_in[7];
  float* out = (float*)d_out;

  char* ws = (char*)d_ws;
  const size_t xtp_bytes = (size_t)16 * 4356 * 256 * 2;    // 35,684,352
  const size_t agg_bytes = (size_t)16 * 9 * 256 * 256 * 2; // 18,874,368
  unsigned short* xTp = (unsigned short*)ws;
  unsigned short* agg = (unsigned short*)(ws + xtp_bytes);
  float* pooled = (float*)(ws + xtp_bytes + agg_bytes);
  float* att = (float*)(ws + xtp_bytes + agg_bytes + 16384);

  border_kernel<<<dim3(260, 16), 256, 0, stream>>>(xTp);
  transpose_kernel<<<1024, 256, 0, stream>>>(x, xTp);
  pool_kernel<<<4096, 256, 0, stream>>>(x, pooled);
  attn_kernel<<<1, 256, 0, stream>>>(pooled, w1, bng, bnb, bnm, bnv, w2, att);
  agg_kernel<<<dim3(256, 2), 256, 0, stream>>>(att, wgt, agg);
  conv_kernel<<<512, 512, 0, stream>>>(xTp, agg, out);
}

// Round 6
// 121.220 us; speedup vs baseline: 1.3659x; 1.0066x over previous
//
#include <hip/hip_runtime.h>

typedef __attribute__((ext_vector_type(8))) short bf16x8;
typedef __attribute__((ext_vector_type(4))) float f32x4;

#define AS3 __attribute__((address_space(3)))
#define AS1 __attribute__((address_space(1)))

__device__ __forceinline__ unsigned short f2bf(float f) {
  unsigned u = __float_as_uint(f);
  u += 0x7fffu + ((u >> 16) & 1u);
  return (unsigned short)(u >> 16);
}
__device__ __forceinline__ float bf2f(unsigned short v) {
  return __uint_as_float((unsigned)v << 16);
}

// ---------------- kernel 1: transpose + pad + bf16 convert (pure) ----------
// x[b][c][y][x] -> xTp[b][(y+1)*66+(x+1)][c] bf16 (borders zeroed separately)
__global__ void transpose_kernel(const float* __restrict__ x,
                                 unsigned short* __restrict__ xTp) {
  __shared__ unsigned short tb[64][258];
  const int blk = blockIdx.x;
  const int b = blk >> 6, y = blk & 63;
  const int t = threadIdx.x;
  const int l = t & 63, w = t >> 6;
  const int coff = l >> 4;          // 0..3 channel sub-offset
  const int x4 = (l & 15) << 2;     // 0..60 x base
  const float* src = x + (size_t)b * 256 * 4096 + (size_t)y * 64;
#pragma unroll 4
  for (int i = 0; i < 16; ++i) {
    const int c = w * 64 + i * 4 + coff;
    const float4 v = *reinterpret_cast<const float4*>(&src[(size_t)c * 4096 + x4]);
    tb[x4 + 0][c] = f2bf(v.x);
    tb[x4 + 1][c] = f2bf(v.y);
    tb[x4 + 2][c] = f2bf(v.z);
    tb[x4 + 3][c] = f2bf(v.w);
  }
  __syncthreads();
  unsigned short* dst = xTp + (size_t)b * (4356 * 256) + ((size_t)(y + 1) * 66 + 1) * 256;
#pragma unroll 4
  for (int i = 0; i < 16; ++i) {
    const int xx = w * 16 + i;
    ushort2 v0 = *(const ushort2*)&tb[xx][l * 4];
    ushort2 v1 = *(const ushort2*)&tb[xx][l * 4 + 2];
    ushort4 v = {v0.x, v0.y, v1.x, v1.y};
    *(ushort4*)&dst[(size_t)xx * 256 + l * 4] = v;
  }
}

// ---------------- kernel 1b: zero the pad borders of xTp ----------------
__global__ void border_kernel(unsigned short* __restrict__ xTp) {
  const int br = blockIdx.x;  // 0..259
  const int b = blockIdx.y;
  int y, xx;
  if (br < 66) { y = 0; xx = br; }
  else if (br < 132) { y = 65; xx = br - 66; }
  else { const int k = br - 132; y = 1 + (k >> 1); xx = (k & 1) * 65; }
  xTp[((size_t)b * 4356 + y * 66 + xx) * 256 + threadIdx.x] = 0;
}

// ---------------- kernel 1c: pool from xTp (bf16, vectorized) ----------
// block (b, ych): 256 rows; thread group t>>5 handles rows r%8, 8 ch each
__global__ void pool2_kernel(const unsigned short* __restrict__ xTp,
                             float* __restrict__ pooled) {
  __shared__ float red[8][256];
  const int b = blockIdx.x;     // 16
  const int ych = blockIdx.y;   // 16
  const int t = threadIdx.x;    // 256
  const int rg = t >> 5;        // 0..7 row group
  const int c8 = (t & 31) << 3; // channel base
  const unsigned short* base = xTp + (size_t)b * (4356 * 256);
  float s[8];
#pragma unroll
  for (int k = 0; k < 8; ++k) s[k] = 0.f;
  for (int rr = 0; rr < 32; ++rr) {
    const int r = rr * 8 + rg;          // 0..255 within the 4-y chunk
    const int y = ych * 4 + (r >> 6);
    const int xx = r & 63;
    const unsigned short* row =
        base + ((size_t)(y + 1) * 66 + 1 + xx) * 256 + c8;
    bf16x8 v = *reinterpret_cast<const bf16x8*>(row);
#pragma unroll
    for (int k = 0; k < 8; ++k) s[k] += bf2f((unsigned short)v[k]);
  }
#pragma unroll
  for (int k = 0; k < 8; ++k) red[rg][c8 + k] = s[k];
  __syncthreads();
  float tot = 0.f;
#pragma unroll
  for (int g = 0; g < 8; ++g) tot += red[g][t];
  atomicAdd(&pooled[b * 256 + t], tot * (1.0f / 4096.0f));
}

// ---------------- kernel 2: attention MLP + softmax ----------------
__global__ void attn_kernel(const float* __restrict__ pooled,
                            const float* __restrict__ w1,
                            const float* __restrict__ bng,
                            const float* __restrict__ bnb,
                            const float* __restrict__ bnm,
                            const float* __restrict__ bnv,
                            const float* __restrict__ w2,
                            float* __restrict__ att) {
  __shared__ float hbuf[256];
  const int t = threadIdx.x;
  const int b = t >> 4, i = t & 15;
  float s = 0.f;
  for (int c = 0; c < 256; ++c) s += pooled[b * 256 + c] * w1[i * 256 + c];
  float h = (s - bnm[i]) * rsqrtf(bnv[i] + 1e-5f) * bng[i] + bnb[i];
  hbuf[t] = fmaxf(h, 0.f);
  __syncthreads();
  if (t < 64) {
    const int bb = t >> 2, k = t & 3;
    float l = 0.f;
    for (int j = 0; j < 16; ++j) l += hbuf[bb * 16 + j] * w2[k * 16 + j];
    float m = l;
    m = fmaxf(m, __shfl_xor(m, 1, 64));
    m = fmaxf(m, __shfl_xor(m, 2, 64));
    float e = expf(l - m);
    float sum = e;
    sum += __shfl_xor(sum, 1, 64);
    sum += __shfl_xor(sum, 2, 64);
    att[bb * 4 + k] = e / sum;
  }
}

// ---------------- kernel 3: aggregate per-sample kernels ----------------
__global__ void agg_kernel(const float* __restrict__ att,
                           const float* __restrict__ wgt,
                           unsigned short* __restrict__ agg) {
  const int o = blockIdx.x;    // 256
  const int bh = blockIdx.y;   // 0..1
  const int c = threadIdx.x;   // 256
  float w[4][9];
#pragma unroll
  for (int k = 0; k < 4; ++k) {
    const float* wp = wgt + ((size_t)((k << 8) + o) * 256 + c) * 9;
#pragma unroll
    for (int t = 0; t < 9; ++t) w[k][t] = wp[t];
  }
  __shared__ float attS[64];
  if (c < 64) attS[c] = att[c];
  __syncthreads();
#pragma unroll 1
  for (int b = bh * 8; b < bh * 8 + 8; ++b) {
    const float a0 = attS[b * 4 + 0], a1 = attS[b * 4 + 1];
    const float a2 = attS[b * 4 + 2], a3 = attS[b * 4 + 3];
#pragma unroll
    for (int t = 0; t < 9; ++t) {
      const float v = a0 * w[0][t] + a1 * w[1][t] + a2 * w[2][t] + a3 * w[3][t];
      agg[(((size_t)(b * 9 + t) * 256) + o) * 256 + c] = f2bf(v);
    }
  }
}

// ---------------- kernel 4: per-sample implicit-GEMM conv (bf16 MFMA) ----
// tile 256(p) x 128(cout); 4 waves (2Mx2N), per-wave 128x64 (8x4 frags)
// -> LDS read traffic 96KB/CU/tap < MFMA 1242cyc (was 128KB, LDS-bound).
// A-halo (396 rows) staged once per c0, reused 9 taps; B ring-4 vmcnt(2).
__global__ __launch_bounds__(256, 2) void conv_kernel(
    const unsigned short* __restrict__ xTp,
    const unsigned short* __restrict__ agg,
    float* __restrict__ out) {
  // A: 448 rows x 64B = 28672 B ; B: 4 slots x 8192 B = 32768 B
  __shared__ unsigned short lds[448 * 32 + 4 * 128 * 32];
  AS3 char* ldsA3 = (AS3 char*)lds;
  AS3 char* ldsB3 = ((AS3 char*)lds) + 28672;

  const int bid = blockIdx.x;
  const int b = bid & 15;   // XCD = b%8
  const int rest = bid >> 4;
  const int mt = rest >> 1;  // 0..15
  const int nh = rest & 1;
  const int p0 = mt << 8;
  const int rowA0 = mt * 264;

  const int tid = threadIdx.x;   // 0..255
  const int lane = tid & 63;
  const int wave = tid >> 6;     // 0..3
  const int wm = wave >> 1;      // 0..1 (M half, 128 rows)
  const int wn = wave & 1;       // 0..1 (N half, 64 cols)

  // staging: thread t -> LDS row t>>2 (+64*issue), linear slot t&3;
  // source col pre-swizzled by swz(row) = (row>>1)&3 = (t>>3)&3
  const int srow = tid >> 2;     // 0..63
  const int scol = ((tid & 3) ^ ((tid >> 3) & 3)) << 3;
  const int sdst = srow * 64 + (tid & 3) * 16;

  const unsigned short* xbs =
      xTp + (size_t)b * (4356 * 256) + (size_t)rowA0 * 256 + scol;
  const unsigned short* aggs =
      agg + ((size_t)(b * 9) * 256 + nh * 128 + srow) * 256 + scol;

  auto stageA = [&](int c0) {
#pragma unroll
    for (int i = 0; i < 7; ++i) {
      const int h = srow + (i << 6);
      const int hs = h > 395 ? 395 : h;
      __builtin_amdgcn_global_load_lds(
          (const AS1 void*)(xbs + (size_t)hs * 256 + c0 * 32),
          (AS3 void*)(ldsA3 + sdst + (i << 12)), 16, 0, 0);
    }
  };
  auto stageB = [&](int c02, int tap2, int slot) {
#pragma unroll
    for (int j = 0; j < 2; ++j) {
      __builtin_amdgcn_global_load_lds(
          (const AS1 void*)(aggs + tap2 * 65536 + (j << 14) + c02 * 32),
          (AS3 void*)(ldsB3 + slot * 8192 + sdst + (j << 12)), 16, 0, 0);
    }
  };

  const int l15 = lane & 15;
  const int lhi = lane >> 4;
  const int hb0 = wm * 132 + l15;  // A halo row base (m=0, tap 0,0)
  const int rslotB = (lhi ^ ((l15 >> 1) & 3)) << 4;
  int boffs[4];
#pragma unroll
  for (int n = 0; n < 4; ++n)
    boffs[n] = 28672 + (wn * 64 + n * 16 + l15) * 64 + rslotB;

  f32x4 acc[8][4];
#pragma unroll
  for (int m = 0; m < 8; ++m)
#pragma unroll
    for (int n = 0; n < 4; ++n) acc[m][n] = (f32x4){0.f, 0.f, 0.f, 0.f};

  stageB(0, 0, 0);
  stageB(0, 1, 1);

#pragma unroll 1
  for (int c0 = 0; c0 < 8; ++c0) {
    __builtin_amdgcn_s_barrier();  // all waves done reading A[c0-1]
    stageA(c0);
    asm volatile("s_waitcnt vmcnt(0)" ::: "memory");
    __builtin_amdgcn_s_barrier();
#pragma unroll
    for (int tap = 0; tap < 9; ++tap) {
      if (tap != 0) {
        asm volatile("s_waitcnt vmcnt(2)" ::: "memory");  // B[tap] landed
        __builtin_amdgcn_s_barrier();
      }
      __builtin_amdgcn_sched_barrier(0);
      const int dy = tap / 3, dx = tap % 3;
      const int slotR = (c0 + tap) & 3;
      bf16x8 af[8], bfr[4];
#pragma unroll
      for (int m = 0; m < 8; ++m) {
        const int h = hb0 + ((m >> 2) + dy) * 66 + (m & 3) * 16 + dx;
        const int ab = h * 64 + ((lhi ^ ((h >> 1) & 3)) << 4);
        af[m] = *(const bf16x8*)((const char*)lds + ab);
      }
#pragma unroll
      for (int n = 0; n < 4; ++n)
        bfr[n] = *(const bf16x8*)((const char*)lds + slotR * 8192 + boffs[n]);
      int c02, tap2;
      if (tap <= 6) { c02 = c0; tap2 = tap + 2; }
      else { c02 = c0 + 1; tap2 = tap - 7; }
      if (c02 > 7) { c02 = 7; tap2 = 8; }  // tail dup, keeps vmcnt uniform
      stageB(c02, tap2, (c0 + tap + 2) & 3);
      __builtin_amdgcn_s_setprio(1);
#pragma unroll
      for (int m = 0; m < 8; ++m)
#pragma unroll
        for (int n = 0; n < 4; ++n)
          acc[m][n] = __builtin_amdgcn_mfma_f32_16x16x32_bf16(af[m], bfr[n],
                                                              acc[m][n], 0, 0, 0);
      __builtin_amdgcn_s_setprio(0);
    }
  }

  // epilogue: D row=(lane>>4)*4+reg is p, col=lane&15 is cout
#pragma unroll
  for (int m = 0; m < 8; ++m) {
    const int p = p0 + wm * 128 + (m >> 2) * 64 + (m & 3) * 16 + (lhi << 2);
#pragma unroll
    for (int n = 0; n < 4; ++n) {
      const int co = nh * 128 + wn * 64 + n * 16 + l15;
      float* dst = out + ((size_t)(b * 256 + co) << 12) + p;
      *reinterpret_cast<f32x4*>(dst) = acc[m][n];
    }
  }
}

extern "C" void kernel_launch(void* const* d_in, const int* in_sizes, int n_in,
                              void* d_out, int out_size, void* d_ws, size_t ws_size,
                              hipStream_t stream) {
  const float* x = (const float*)d_in[0];
  const float* w1 = (const float*)d_in[1];
  const float* bng = (const float*)d_in[2];
  const float* bnb = (const float*)d_in[3];
  const float* bnm = (const float*)d_in[4];
  const float* bnv = (const float*)d_in[5];
  const float* w2 = (const float*)d_in[6];
  const float* wgt = (const float*)d_in[7];
  float* out = (float*)d_out;

  char* ws = (char*)d_ws;
  const size_t xtp_bytes = (size_t)16 * 4356 * 256 * 2;    // 35,684,352
  const size_t agg_bytes = (size_t)16 * 9 * 256 * 256 * 2; // 18,874,368
  unsigned short* xTp = (unsigned short*)ws;
  unsigned short* agg = (unsigned short*)(ws + xtp_bytes);
  float* pooled = (float*)(ws + xtp_bytes + agg_bytes);
  float* att = (float*)(ws + xtp_bytes + agg_bytes + 16384);

  hipMemsetAsync(pooled, 0, 16 * 256 * sizeof(float), stream);
  border_kernel<<<dim3(260, 16), 256, 0, stream>>>(xTp);
  transpose_kernel<<<1024, 256, 0, stream>>>(x, xTp);
  pool2_kernel<<<dim3(16, 16), 256, 0, stream>>>(xTp, pooled);
  attn_kernel<<<1, 256, 0, stream>>>(pooled, w1, bng, bnb, bnm, bnv, w2, att);
  agg_kernel<<<dim3(256, 2), 256, 0, stream>>>(att, wgt, agg);
  conv_kernel<<<512, 256, 0, stream>>>(xTp, agg, out);
}